// Round 8
// baseline (341.409 us; speedup 1.0000x reference)
//
#include <hip/hip_runtime.h>
#include <stdint.h>

#define NTOK 4096
#define CDIM 512
#define HEADS 8
#define DHEAD 64
#define PHEAD (NTOK * DHEAD)          // 262144 elems per head per tensor

typedef __bf16 bf16x8 __attribute__((ext_vector_type(8)));
typedef float f32x4 __attribute__((ext_vector_type(4)));

__device__ __forceinline__ unsigned short bfbits(float f) {
    return __builtin_bit_cast(unsigned short, (__bf16)f);   // hw v_cvt on gfx950
}

__device__ __forceinline__ f32x4 mfma32(bf16x8 a, bf16x8 b, f32x4 c) {
    return __builtin_amdgcn_mfma_f32_16x16x32_bf16(a, b, c, 0, 0, 0);
}

// stage 8 fp32 elems as bf16 into LDS (fused cast)
__device__ __forceinline__ void stage8(unsigned short* dst, const float* src) {
    const float4 v0 = *(const float4*)src;
    const float4 v1 = *(const float4*)(src + 4);
    ushort4 o0, o1;
    o0.x = bfbits(v0.x); o0.y = bfbits(v0.y); o0.z = bfbits(v0.z); o0.w = bfbits(v0.w);
    o1.x = bfbits(v1.x); o1.y = bfbits(v1.y); o1.z = bfbits(v1.z); o1.w = bfbits(v1.w);
    *(ushort4*)dst = o0;
    *(ushort4*)(dst + 4) = o1;
}

// ---------------- QKV GEMM: fp32 in (cast fused into staging), 128x128 tile ----------------
__global__ __launch_bounds__(256) void gemm_qkv(
    const float* __restrict__ A,            // x  [4096][512] fp32
    const float* __restrict__ Bm,           // Wqkv [1536][512] fp32
    const float* __restrict__ bias,
    const float* __restrict__ scale_p,
    unsigned short* __restrict__ qkv_out)
{
    const int K = CDIM;
    __shared__ __align__(16) unsigned short smem[128 * 136];   // 34816 B
    unsigned short* lA = smem;              // 128*32
    unsigned short* lB = smem + 4096;       // 128*32

    const int tid = threadIdx.x;
    const int mBase = blockIdx.y * 128, nBase = blockIdx.x * 128;
    const int lane = tid & 63;
    const int w = __builtin_amdgcn_readfirstlane(tid >> 6);
    const int l16 = lane & 15, quad = lane >> 4;
    const int wr = (w >> 1) * 64, wc = (w & 1) * 64;
    const int srow = tid >> 2, scol = (tid & 3) * 8;

    f32x4 acc[4][4] = {};

    for (int kt = 0; kt < K; kt += 32) {
        __syncthreads();
#pragma unroll
        for (int p = 0; p < 2; ++p) {
            const int r = p * 64 + srow;
            stage8(&lA[r * 32 + scol], &A[(size_t)(mBase + r) * K + kt + scol]);
            stage8(&lB[r * 32 + scol], &Bm[(size_t)(nBase + r) * K + kt + scol]);
        }
        __syncthreads();

        bf16x8 af[4], bfr[4];
#pragma unroll
        for (int i = 0; i < 4; ++i)
            af[i] = *(const bf16x8*)&lA[(wr + i * 16 + l16) * 32 + quad * 8];
#pragma unroll
        for (int j = 0; j < 4; ++j)
            bfr[j] = *(const bf16x8*)&lB[(wc + j * 16 + l16) * 32 + quad * 8];
#pragma unroll
        for (int i = 0; i < 4; ++i)
#pragma unroll
            for (int j = 0; j < 4; ++j)
                acc[i][j] = mfma32(af[i], bfr[j], acc[i][j]);
    }

    const int three = nBase >> 9;               // block-uniform: 0 q, 1 k, 2 v
    const float scl = scale_p[0] * 1.44269504f; // fold log2(e) for exp2 softmax
    const float mul = (three == 0) ? scl : 1.0f;

    __syncthreads();
#pragma unroll
    for (int i = 0; i < 4; ++i)
#pragma unroll
        for (int j = 0; j < 4; ++j)
#pragma unroll
            for (int r = 0; r < 4; ++r) {
                const int rl = wr + i * 16 + quad * 4 + r;
                const int cl = wc + j * 16 + l16;
                const float v = (acc[i][j][r] + bias[nBase + cl]) * mul;
                smem[rl * 136 + cl] = bfbits(v);
            }
    __syncthreads();

    const size_t base3 = (size_t)three * (PHEAD * HEADS);
    if (three < 2) {
        // Q/K frag layout [h][t16][d2][quad*16+l16][8]
#pragma unroll
        for (int pass = 0; pass < 8; ++pass) {
            const int idx = pass * 256 + tid;
            const int rl16 = idx & 15, qc = (idx >> 4) & 7;
            const int hsel = (idx >> 7) & 1, t16l = (idx >> 8) & 7;
            const uint4 d = *(const uint4*)&smem[(t16l * 16 + rl16) * 136 + hsel * 64 + qc * 8];
            const int hh = ((nBase >> 6) + hsel) & 7;
            const int t16 = (mBase >> 4) + t16l;
            const size_t dst = base3 + (size_t)hh * PHEAD +
                (size_t)(((t16 * 2 + (qc >> 2)) * 64 + (qc & 3) * 16 + rl16) * 8);
            *(uint4*)&qkv_out[dst] = d;
        }
    } else {
        // V frag layout [h][k32][dt][quad*16+l16][8] (key-permuted for PV mfma32)
#pragma unroll
        for (int pass = 0; pass < 8; ++pass) {
            const int idx = pass * 256 + tid;
            const int l16t = idx & 15, quadt = (idx >> 4) & 3;
            const int dt = (idx >> 6) & 3, k32l = (idx >> 8) & 3, hsel = (idx >> 10) & 1;
            const int col = hsel * 64 + dt * 16 + l16t;
            unsigned short o8[8];
#pragma unroll
            for (int e = 0; e < 4; ++e) {
                o8[e]     = smem[(k32l * 32 + quadt * 4 + e) * 136 + col];
                o8[e + 4] = smem[(k32l * 32 + 16 + quadt * 4 + e) * 136 + col];
            }
            const int hh = ((nBase >> 6) + hsel) & 7;
            const int k32 = (mBase >> 5) + k32l;
            const size_t dst = base3 + (size_t)hh * PHEAD +
                (size_t)(((k32 * 4 + dt) * 64 + quadt * 16 + l16t) * 8);
            *(uint4*)&qkv_out[dst] = *(uint4*)o8;
        }
    }
}

// ---------------- flash attention v7: Q-tile 64 + 2 key-slices + fp32 atomic merge ----------------
// grid (8, 64, 2): x = head (XCD-local K/V), z = key-slice of 2048 keys.
// 4 waves split the slice 4-way (512 keys each, 16 groups of 32); flash4's
// register body (K ping-pong prefetch, no loop LDS/barriers/cross-lane).
// Epilogue: 2-buffer LDS wave-merge -> coalesced fp32 atomicAdd of UNNORMALIZED
// O into attn_acc, l into l_acc. Normalization happens in gemm_proj staging.
__global__ __launch_bounds__(256, 2) void flash7_k(
    const unsigned short* __restrict__ qf,
    const unsigned short* __restrict__ kf,
    const unsigned short* __restrict__ vf,
    float* __restrict__ attn_acc,   // [4096][512] fp32 (zeroed)
    float* __restrict__ l_acc)      // [8][4096] fp32 (zeroed)
{
    __shared__ float ldsO[2][64][68];   // 34816 B

    const int tid = threadIdx.x;
    const int lane = tid & 63;
    const int w = __builtin_amdgcn_readfirstlane(tid >> 6);
    const int l16 = lane & 15, quad = lane >> 4;
    const int h = blockIdx.x, qb = blockIdx.y, ks = blockIdx.z;

    const unsigned short* qh = qf + (size_t)h * PHEAD;
    const unsigned short* kb = kf + (size_t)h * PHEAD + ks * 131072 + w * 32768;
    const unsigned short* vb = vf + (size_t)h * PHEAD + ks * 131072 + w * 32768;

    bf16x8 qfr[4][2];
#pragma unroll
    for (int qt = 0; qt < 4; ++qt)
#pragma unroll
        for (int d2 = 0; d2 < 2; ++d2)
            qfr[qt][d2] = *(const bf16x8*)&qh[((qb * 4 + qt) * 2 + d2) * 512 + lane * 8];

    bf16x8 ones;
#pragma unroll
    for (int j = 0; j < 8; ++j) ones[j] = (__bf16)1.0f;

    f32x4 oacc[4][4] = {};   // [dtile][qtile]: O^T  d=quad*4+r, q=l16
    f32x4 lacc[4] = {};      // [qtile] (replicated across quads/regs)

    bf16x8 kA[4], kB[4];
#pragma unroll
    for (int i = 0; i < 4; ++i)
        kA[i] = *(const bf16x8*)&kb[i * 512 + lane * 8];

    // one 32-key group; prefetches group g+1's K (g=15 overread lands in V region — safe)
    auto body = [&](int g, bf16x8* kuse, bf16x8* kload) {
#pragma unroll
        for (int i = 0; i < 4; ++i)
            kload[i] = *(const bf16x8*)&kb[(g + 1) * 2048 + i * 512 + lane * 8];
        bf16x8 vc[4];
#pragma unroll
        for (int i = 0; i < 4; ++i)
            vc[i] = *(const bf16x8*)&vb[g * 2048 + i * 512 + lane * 8];

        f32x4 s[2][4];
#pragma unroll
        for (int kt = 0; kt < 2; ++kt)
#pragma unroll
            for (int qt = 0; qt < 4; ++qt) {
                f32x4 a = {};
                a = mfma32(kuse[kt * 2 + 0], qfr[qt][0], a);
                a = mfma32(kuse[kt * 2 + 1], qfr[qt][1], a);
                s[kt][qt] = a;
            }

        bf16x8 pf[4];
#pragma unroll
        for (int qt = 0; qt < 4; ++qt) {
            bf16x8 pb;
#pragma unroll
            for (int kt = 0; kt < 2; ++kt)
#pragma unroll
                for (int r = 0; r < 4; ++r)
                    pb[kt * 4 + r] = (__bf16)__builtin_amdgcn_exp2f(s[kt][qt][r]);
            pf[qt] = pb;
            lacc[qt] = mfma32(ones, pb, lacc[qt]);   // l += sum_k P (MFMA pipe)
        }
#pragma unroll
        for (int dt = 0; dt < 4; ++dt)
#pragma unroll
            for (int qt = 0; qt < 4; ++qt)
                oacc[dt][qt] = mfma32(vc[dt], pf[qt], oacc[dt][qt]);
    };

    for (int it = 0; it < 8; ++it) {
        body(it * 2 + 0, kA, kB);
        body(it * 2 + 1, kB, kA);
    }

    // ---- epilogue: 2-buffer LDS merge (waves 0/2 write, 1/3 add), then atomics ----
    if (w == 0 || w == 2) {
        const int b = w >> 1;
#pragma unroll
        for (int qt = 0; qt < 4; ++qt)
#pragma unroll
            for (int dt = 0; dt < 4; ++dt)
                *(f32x4*)&ldsO[b][qt * 16 + l16][dt * 16 + quad * 4] = oacc[dt][qt];
    }
    if (quad == 0) {
#pragma unroll
        for (int qt = 0; qt < 4; ++qt)
            atomicAdd(&l_acc[h * NTOK + qb * 64 + qt * 16 + l16], lacc[qt][0]);
    }
    __syncthreads();
    if (w == 1 || w == 3) {
        const int b = w >> 1;
#pragma unroll
        for (int qt = 0; qt < 4; ++qt)
#pragma unroll
            for (int dt = 0; dt < 4; ++dt) {
                float* p = &ldsO[b][qt * 16 + l16][dt * 16 + quad * 4];
                const f32x4 prev = *(const f32x4*)p;
                *(f32x4*)p = prev + oacc[dt][qt];
            }
    }
    __syncthreads();
    {
        const int q = tid >> 2, db = (tid & 3) * 16;
        float* dst = &attn_acc[(size_t)(qb * 64 + q) * CDIM + h * DHEAD + db];
#pragma unroll
        for (int j = 0; j < 16; ++j)
            atomicAdd(dst + j, ldsO[0][q][db + j] + ldsO[1][q][db + j]);
    }
}

// ---------------- proj GEMM: A = attn_acc/l (fp32, normalize+cast fused), B fp32 ----------------
__global__ __launch_bounds__(256) void gemm_proj(
    const float* __restrict__ A,            // attn_acc [4096][512] fp32 (unnormalized)
    const float* __restrict__ l_acc,        // [8][4096]
    const float* __restrict__ Bm,           // Wproj [512][512] fp32
    const float* __restrict__ bias,
    float* __restrict__ c_out)              // [4096][512] fp32
{
    const int K = CDIM, Nn = CDIM;
    __shared__ __align__(16) unsigned short smem[128 * 64];   // 16 KB
    unsigned short* lA = smem;
    unsigned short* lB = smem + 4096;

    const int tid = threadIdx.x;
    const int mBase = blockIdx.y * 128, nBase = blockIdx.x * 128;
    const int lane = tid & 63;
    const int w = __builtin_amdgcn_readfirstlane(tid >> 6);
    const int l16 = lane & 15, quad = lane >> 4;
    const int wr = (w >> 1) * 64, wc = (w & 1) * 64;
    const int srow = tid >> 2, scol = (tid & 3) * 8;

    f32x4 acc[4][4] = {};

    for (int kt = 0; kt < K; kt += 32) {
        const int head = kt >> 6;   // 32 | kt and heads are 64 wide -> uniform per iter
        __syncthreads();
#pragma unroll
        for (int p = 0; p < 2; ++p) {
            const int r = p * 64 + srow;
            // A: normalize by l then cast
            const float invl = __builtin_amdgcn_rcpf(l_acc[head * NTOK + mBase + r]);
            const float4 v0 = *(const float4*)&A[(size_t)(mBase + r) * K + kt + scol];
            const float4 v1 = *(const float4*)&A[(size_t)(mBase + r) * K + kt + scol + 4];
            ushort4 o0, o1;
            o0.x = bfbits(v0.x * invl); o0.y = bfbits(v0.y * invl);
            o0.z = bfbits(v0.z * invl); o0.w = bfbits(v0.w * invl);
            o1.x = bfbits(v1.x * invl); o1.y = bfbits(v1.y * invl);
            o1.z = bfbits(v1.z * invl); o1.w = bfbits(v1.w * invl);
            *(ushort4*)&lA[r * 32 + scol] = o0;
            *(ushort4*)&lA[r * 32 + scol + 4] = o1;
            // B: plain cast
            stage8(&lB[r * 32 + scol], &Bm[(size_t)(nBase + r) * K + kt + scol]);
        }
        __syncthreads();

        bf16x8 af[4], bfr[4];
#pragma unroll
        for (int i = 0; i < 4; ++i)
            af[i] = *(const bf16x8*)&lA[(wr + i * 16 + l16) * 32 + quad * 8];
#pragma unroll
        for (int j = 0; j < 4; ++j)
            bfr[j] = *(const bf16x8*)&lB[(wc + j * 16 + l16) * 32 + quad * 8];
#pragma unroll
        for (int i = 0; i < 4; ++i)
#pragma unroll
            for (int j = 0; j < 4; ++j)
                acc[i][j] = mfma32(af[i], bfr[j], acc[i][j]);
    }

#pragma unroll
    for (int i = 0; i < 4; ++i)
#pragma unroll
        for (int j = 0; j < 4; ++j)
#pragma unroll
            for (int r = 0; r < 4; ++r) {
                const int grow = mBase + wr + i * 16 + quad * 4 + r;
                const int gcol = nBase + wc + j * 16 + l16;
                c_out[(size_t)grow * Nn + gcol] = acc[i][j][r] + bias[gcol];
            }
}

extern "C" void kernel_launch(void* const* d_in, const int* in_sizes, int n_in,
                              void* d_out, int out_size, void* d_ws, size_t ws_size,
                              hipStream_t stream) {
    const float* x       = (const float*)d_in[0];
    const float* scale_p = (const float*)d_in[3];
    const float* Wqkv    = (const float*)d_in[4];
    const float* bqkv    = (const float*)d_in[5];
    const float* Wproj   = (const float*)d_in[6];
    const float* bproj   = (const float*)d_in[7];
    float* out = (float*)d_out;

    char* ws = (char*)d_ws;
    const size_t OFF_QKV  = 0;                        // 3*8*PHEAD bf16 = 12 MB
    const size_t OFF_ATTN = 12582912;                 // 4096*512 fp32  = 8 MB
    const size_t OFF_L    = OFF_ATTN + 8388608;       // 8*4096 fp32    = 128 KB
    const size_t NEEDED   = OFF_L + 131072;           // ~20.1 MB
    if (ws_size < NEEDED) return;

    unsigned short* qkvb = (unsigned short*)(ws + OFF_QKV);
    float* attn_acc = (float*)(ws + OFF_ATTN);
    float* l_acc    = (float*)(ws + OFF_L);

    // zero the fp32 accumulators (attn + l are contiguous)
    hipMemsetAsync(attn_acc, 0, 8388608 + 131072, stream);

    gemm_qkv<<<dim3(12, 32), 256, 0, stream>>>(x, Wqkv, bqkv, scale_p, qkvb);

    const unsigned short* qfr = qkvb;
    const unsigned short* kfr = qkvb + (size_t)PHEAD * HEADS;
    const unsigned short* vfr = qkvb + (size_t)2 * PHEAD * HEADS;
    flash7_k<<<dim3(8, 64, 2), 256, 0, stream>>>(qfr, kfr, vfr, attn_acc, l_acc);

    gemm_proj<<<dim3(4, 32), 256, 0, stream>>>(attn_acc, l_acc, Wproj, bproj, out);
}

// Round 11
// 139.706 us; speedup vs baseline: 2.4438x; 2.4438x over previous
//
#include <hip/hip_runtime.h>
#include <stdint.h>

#define NTOK 4096
#define CDIM 512
#define HEADS 8
#define DHEAD 64
#define PHEAD (NTOK * DHEAD)          // 262144 elems per head per tensor

typedef __bf16 bf16x8 __attribute__((ext_vector_type(8)));
typedef float f32x4 __attribute__((ext_vector_type(4)));

__device__ __forceinline__ unsigned short bfbits(float f) {
    return __builtin_bit_cast(unsigned short, (__bf16)f);   // hw v_cvt on gfx950
}

__device__ __forceinline__ f32x4 mfma32(bf16x8 a, bf16x8 b, f32x4 c) {
    return __builtin_amdgcn_mfma_f32_16x16x32_bf16(a, b, c, 0, 0, 0);
}

// stage 8 fp32 elems as bf16 into LDS (fused cast)
__device__ __forceinline__ void stage8(unsigned short* dst, const float* src) {
    const float4 v0 = *(const float4*)src;
    const float4 v1 = *(const float4*)(src + 4);
    ushort4 o0, o1;
    o0.x = bfbits(v0.x); o0.y = bfbits(v0.y); o0.z = bfbits(v0.z); o0.w = bfbits(v0.w);
    o1.x = bfbits(v1.x); o1.y = bfbits(v1.y); o1.z = bfbits(v1.z); o1.w = bfbits(v1.w);
    *(ushort4*)dst = o0;
    *(ushort4*)(dst + 4) = o1;
}

// ---------------- QKV GEMM: 64x128 tiles (768 blocks = 3/CU exact), fused fp32 cast ----------
// C = x * Wqkv^T + bqkv -> scatter bf16 into pre-fragmented q/k/v layouts (q *= scale*log2e)
__global__ __launch_bounds__(256) void gemm_qkv(
    const float* __restrict__ A,            // x  [4096][512] fp32
    const float* __restrict__ Bm,           // Wqkv [1536][512] fp32
    const float* __restrict__ bias,
    const float* __restrict__ scale_p,
    unsigned short* __restrict__ qkv_out)
{
    __shared__ __align__(16) unsigned short smem[64 * 136];   // 17408 B
    unsigned short* lA = smem;              // 64*32
    unsigned short* lB = smem + 2048;       // 128*32

    const int tid = threadIdx.x;
    const int mBase = blockIdx.y * 64, nBase = blockIdx.x * 128;
    const int lane = tid & 63;
    const int w = __builtin_amdgcn_readfirstlane(tid >> 6);
    const int l16 = lane & 15, quad = lane >> 4;
    const int srow = tid >> 2, scol = (tid & 3) * 8;

    f32x4 acc[4][2] = {};   // wave w owns cols [w*32, w*32+32), all 64 rows

    for (int kt = 0; kt < CDIM; kt += 32) {
        __syncthreads();
        stage8(&lA[srow * 32 + scol], &A[(size_t)(mBase + srow) * CDIM + kt + scol]);
#pragma unroll
        for (int p = 0; p < 2; ++p) {
            const int r = p * 64 + srow;
            stage8(&lB[r * 32 + scol], &Bm[(size_t)(nBase + r) * CDIM + kt + scol]);
        }
        __syncthreads();

        bf16x8 af[4], bfr[2];
#pragma unroll
        for (int i = 0; i < 4; ++i)
            af[i] = *(const bf16x8*)&lA[(i * 16 + l16) * 32 + quad * 8];
#pragma unroll
        for (int j = 0; j < 2; ++j)
            bfr[j] = *(const bf16x8*)&lB[(w * 32 + j * 16 + l16) * 32 + quad * 8];
#pragma unroll
        for (int i = 0; i < 4; ++i)
#pragma unroll
            for (int j = 0; j < 2; ++j)
                acc[i][j] = mfma32(af[i], bfr[j], acc[i][j]);
    }

    const int three = nBase >> 9;               // block-uniform: 0 q, 1 k, 2 v
    const float scl = scale_p[0] * 1.44269504f; // fold log2(e)
    const float mul = (three == 0) ? scl : 1.0f;

    __syncthreads();
#pragma unroll
    for (int i = 0; i < 4; ++i)
#pragma unroll
        for (int j = 0; j < 2; ++j)
#pragma unroll
            for (int r = 0; r < 4; ++r) {
                const int rl = i * 16 + quad * 4 + r;
                const int cl = w * 32 + j * 16 + l16;
                const float v = (acc[i][j][r] + bias[nBase + cl]) * mul;
                smem[rl * 136 + cl] = bfbits(v);
            }
    __syncthreads();

    const size_t base3 = (size_t)three * (PHEAD * HEADS);
    if (three < 2) {
        // Q/K frag layout [h][t16][d2][quad*16+l16][8]
#pragma unroll
        for (int pass = 0; pass < 4; ++pass) {
            const int idx = pass * 256 + tid;
            const int rl16 = idx & 15, qc = (idx >> 4) & 7;
            const int hsel = (idx >> 7) & 1, t16l = (idx >> 8) & 3;
            const uint4 d = *(const uint4*)&smem[(t16l * 16 + rl16) * 136 + hsel * 64 + qc * 8];
            const int hh = ((nBase >> 6) + hsel) & 7;
            const int t16 = (mBase >> 4) + t16l;
            const size_t dst = base3 + (size_t)hh * PHEAD +
                (size_t)(((t16 * 2 + (qc >> 2)) * 64 + (qc & 3) * 16 + rl16) * 8);
            *(uint4*)&qkv_out[dst] = d;
        }
    } else {
        // V frag layout [h][k32][dt][quad*16+l16][8] (key-permuted for PV mfma32)
#pragma unroll
        for (int pass = 0; pass < 4; ++pass) {
            const int idx = pass * 256 + tid;
            const int l16t = idx & 15, quadt = (idx >> 4) & 3;
            const int dt = (idx >> 6) & 3, k32l = (idx >> 8) & 1, hsel = (idx >> 9) & 1;
            const int col = hsel * 64 + dt * 16 + l16t;
            unsigned short o8[8];
#pragma unroll
            for (int e = 0; e < 4; ++e) {
                o8[e]     = smem[(k32l * 32 + quadt * 4 + e) * 136 + col];
                o8[e + 4] = smem[(k32l * 32 + 16 + quadt * 4 + e) * 136 + col];
            }
            const int hh = ((nBase >> 6) + hsel) & 7;
            const int k32 = (mBase >> 5) + k32l;
            const size_t dst = base3 + (size_t)hh * PHEAD +
                (size_t)(((k32 * 4 + dt) * 64 + quadt * 16 + l16t) * 8);
            *(uint4*)&qkv_out[dst] = *(uint4*)o8;
        }
    }
}

// ---------------- flash attention v6 (R7-proven): Q-tile 32, grid (8,128) ----------------
__global__ __launch_bounds__(256, 4) void flash6_k(
    const unsigned short* __restrict__ qf,
    const unsigned short* __restrict__ kf,
    const unsigned short* __restrict__ vf,
    unsigned short* __restrict__ attn_out)   // [N][C] bf16
{
    __shared__ float ldsO[4][32][68];   // 34816 B
    __shared__ float sml[4][32];

    const int tid = threadIdx.x;
    const int lane = tid & 63;
    const int w = __builtin_amdgcn_readfirstlane(tid >> 6);
    const int l16 = lane & 15, quad = lane >> 4;
    const int h = blockIdx.x, qb = blockIdx.y;     // XCD swizzle: x = head

    const unsigned short* qh = qf + (size_t)h * PHEAD;
    const unsigned short* kb = kf + (size_t)h * PHEAD + w * 65536;   // 1024 keys/wave
    const unsigned short* vb = vf + (size_t)h * PHEAD + w * 65536;

    bf16x8 qfr[2][2];
#pragma unroll
    for (int qt = 0; qt < 2; ++qt)
#pragma unroll
        for (int d2 = 0; d2 < 2; ++d2)
            qfr[qt][d2] = *(const bf16x8*)&qh[((qb * 2 + qt) * 2 + d2) * 512 + lane * 8];

    bf16x8 ones;
#pragma unroll
    for (int j = 0; j < 8; ++j) ones[j] = (__bf16)1.0f;

    f32x4 oacc[4][2] = {};   // [dtile][qtile]: O^T  d=quad*4+r, q=l16
    f32x4 lacc[2] = {};

    bf16x8 kA[4], kB[4];
#pragma unroll
    for (int i = 0; i < 4; ++i)
        kA[i] = *(const bf16x8*)&kb[i * 512 + lane * 8];

    auto body = [&](int g, bf16x8* kuse, bf16x8* kload) {
#pragma unroll
        for (int i = 0; i < 4; ++i)
            kload[i] = *(const bf16x8*)&kb[(g + 1) * 2048 + i * 512 + lane * 8];
        bf16x8 vc[4];
#pragma unroll
        for (int i = 0; i < 4; ++i)
            vc[i] = *(const bf16x8*)&vb[g * 2048 + i * 512 + lane * 8];

        f32x4 s[2][2];
#pragma unroll
        for (int kt = 0; kt < 2; ++kt)
#pragma unroll
            for (int qt = 0; qt < 2; ++qt) {
                f32x4 a = {};
                a = mfma32(kuse[kt * 2 + 0], qfr[qt][0], a);
                a = mfma32(kuse[kt * 2 + 1], qfr[qt][1], a);
                s[kt][qt] = a;
            }

        bf16x8 pf[2];
#pragma unroll
        for (int qt = 0; qt < 2; ++qt) {
            bf16x8 pb;
#pragma unroll
            for (int kt = 0; kt < 2; ++kt)
#pragma unroll
                for (int r = 0; r < 4; ++r)
                    pb[kt * 4 + r] = (__bf16)__builtin_amdgcn_exp2f(s[kt][qt][r]);
            pf[qt] = pb;
            lacc[qt] = mfma32(ones, pb, lacc[qt]);   // l += sum_k P (MFMA pipe)
        }
#pragma unroll
        for (int dt = 0; dt < 4; ++dt)
#pragma unroll
            for (int qt = 0; qt < 2; ++qt)
                oacc[dt][qt] = mfma32(vc[dt], pf[qt], oacc[dt][qt]);
    };

    for (int it = 0; it < 16; ++it) {
        body(it * 2 + 0, kA, kB);
        body(it * 2 + 1, kB, kA);
    }

    if (quad == 0) {
#pragma unroll
        for (int qt = 0; qt < 2; ++qt) sml[w][qt * 16 + l16] = lacc[qt][0];
    }
    __syncthreads();
#pragma unroll
    for (int qt = 0; qt < 2; ++qt) {
        const int q = qt * 16 + l16;
#pragma unroll
        for (int dt = 0; dt < 4; ++dt)
            *(f32x4*)&ldsO[w][q][dt * 16 + quad * 4] = oacc[dt][qt];
    }
    __syncthreads();
    {
        const int q = tid >> 3, dseg = (tid & 7) * 8;
        const float L = sml[0][q] + sml[1][q] + sml[2][q] + sml[3][q];
        const float inv = 1.f / L;
        unsigned short o8[8];
#pragma unroll
        for (int i = 0; i < 8; ++i) {
            const float v = ldsO[0][q][dseg + i] + ldsO[1][q][dseg + i] +
                            ldsO[2][q][dseg + i] + ldsO[3][q][dseg + i];
            o8[i] = bfbits(v * inv);
        }
        *(uint4*)&attn_out[(size_t)(qb * 32 + q) * CDIM + h * DHEAD + dseg] = *(uint4*)o8;
    }
}

// ---------------- proj GEMM: 64x64 tiles (512 blocks = 2/CU), fused Wproj cast ----------------
__global__ __launch_bounds__(256) void gemm_proj(
    const unsigned short* __restrict__ A,   // attn [4096][512] bf16
    const float* __restrict__ Bm,           // Wproj [512][512] fp32
    const float* __restrict__ bias,
    float* __restrict__ c_out)              // [4096][512] fp32
{
    __shared__ __align__(16) unsigned short smem[2 * 64 * 32];  // 8 KB
    unsigned short* lA = smem;
    unsigned short* lB = smem + 2048;

    const int tid = threadIdx.x;
    const int mBase = blockIdx.y * 64, nBase = blockIdx.x * 64;
    const int lane = tid & 63;
    const int w = __builtin_amdgcn_readfirstlane(tid >> 6);
    const int l16 = lane & 15, quad = lane >> 4;
    const int srow = tid >> 2, scol = (tid & 3) * 8;

    f32x4 acc[4] = {};   // wave w owns cols [w*16, w*16+16), all 64 rows

    for (int kt = 0; kt < CDIM; kt += 32) {
        __syncthreads();
        *(uint4*)&lA[srow * 32 + scol] =
            *(const uint4*)&A[(size_t)(mBase + srow) * CDIM + kt + scol];
        stage8(&lB[srow * 32 + scol], &Bm[(size_t)(nBase + srow) * CDIM + kt + scol]);
        __syncthreads();

        bf16x8 af[4], bfr;
#pragma unroll
        for (int i = 0; i < 4; ++i)
            af[i] = *(const bf16x8*)&lA[(i * 16 + l16) * 32 + quad * 8];
        bfr = *(const bf16x8*)&lB[(w * 16 + l16) * 32 + quad * 8];
#pragma unroll
        for (int i = 0; i < 4; ++i)
            acc[i] = mfma32(af[i], bfr, acc[i]);
    }

#pragma unroll
    for (int i = 0; i < 4; ++i)
#pragma unroll
        for (int r = 0; r < 4; ++r) {
            const int grow = mBase + i * 16 + quad * 4 + r;
            const int gcol = nBase + w * 16 + l16;
            c_out[(size_t)grow * CDIM + gcol] = acc[i][r] + bias[gcol];
        }
}

extern "C" void kernel_launch(void* const* d_in, const int* in_sizes, int n_in,
                              void* d_out, int out_size, void* d_ws, size_t ws_size,
                              hipStream_t stream) {
    const float* x       = (const float*)d_in[0];
    const float* scale_p = (const float*)d_in[3];
    const float* Wqkv    = (const float*)d_in[4];
    const float* bqkv    = (const float*)d_in[5];
    const float* Wproj   = (const float*)d_in[6];
    const float* bproj   = (const float*)d_in[7];
    float* out = (float*)d_out;

    char* ws = (char*)d_ws;
    const size_t OFF_QKV  = 0;                        // 3*8*PHEAD bf16 = 12 MB
    const size_t OFF_ATTN = 12582912;                 // 4096*512 bf16  = 4 MB
    const size_t NEEDED   = OFF_ATTN + 4194304;       // 16 MB
    if (ws_size < NEEDED) return;

    unsigned short* qkvb  = (unsigned short*)(ws + OFF_QKV);
    unsigned short* attnb = (unsigned short*)(ws + OFF_ATTN);

    gemm_qkv<<<dim3(12, 64), 256, 0, stream>>>(x, Wqkv, bqkv, scale_p, qkvb);

    const unsigned short* qfr = qkvb;
    const unsigned short* kfr = qkvb + (size_t)PHEAD * HEADS;
    const unsigned short* vfr = qkvb + (size_t)2 * PHEAD * HEADS;
    flash6_k<<<dim3(8, 128), 256, 0, stream>>>(qfr, kfr, vfr, attnb);

    gemm_proj<<<dim3(8, 64), 256, 0, stream>>>(attnb, Wproj, bproj, out);
}